// Round 2
// baseline (476.939 us; speedup 1.0000x reference)
//
#include <hip/hip_runtime.h>
#include <hip/hip_bf16.h>
#include <stdint.h>

// Problem constants
#define TOK   25216          // B*N = 128*197
#define CC    768
#define HH    12
#define NKV   224            // 197 padded to 14*16 (and 7*32 for PV k-steps)
#define BHN   1536           // B*H

typedef __attribute__((ext_vector_type(8))) __bf16 bf16x8;   // MFMA A/B frag (4 VGPR)
typedef __attribute__((ext_vector_type(8))) ushort u16x8;
typedef __attribute__((ext_vector_type(4))) float  f32x4;    // MFMA C/D frag

__device__ __forceinline__ ushort f2bf(float f) {
  union { float f; uint32_t u; } v; v.f = f;
  uint32_t u = v.u;
  u += 0x7FFFu + ((u >> 16) & 1u);          // RTNE
  return (ushort)(u >> 16);
}
__device__ __forceinline__ float bf2f(ushort s) {
  union { uint32_t u; float f; } v; v.u = ((uint32_t)s) << 16; return v.f;
}

__device__ __forceinline__ void gload_lds16(const void* g, void* l) {
  __builtin_amdgcn_global_load_lds(
      (const __attribute__((address_space(1))) unsigned int*)g,
      (__attribute__((address_space(3))) unsigned int*)l, 16, 0, 0);
}

// ---------------- f32 -> bf16 convert (vectorized) ----------------
__global__ __launch_bounds__(256) void conv_bf16(const float* __restrict__ in,
                                                 ushort* __restrict__ out, int n) {
  int idx = (blockIdx.x * 256 + threadIdx.x) * 4;
  if (idx < n) {
    float4 v = *(const float4*)(in + idx);
    ushort4 o;
    o.x = f2bf(v.x); o.y = f2bf(v.y); o.z = f2bf(v.z); o.w = f2bf(v.w);
    *(ushort4*)(out + idx) = o;
  }
}

// ---------------- decay mask: M[h][i][j], padded [12][224][224] bf16 ----------------
__global__ __launch_bounds__(256) void mask_kernel(const float* __restrict__ ai,
                                                   const int* __restrict__ ci,
                                                   ushort* __restrict__ Mb) {
  int h = blockIdx.x / NKV;
  int i = blockIdx.x % NKV;
  int j = threadIdx.x;
  if (j >= NKV) return;
  float val;
  if (j >= 197)      val = 0.f;   // unused (forced -inf logit)
  else if (i >= 197) val = 1.f;   // unused (rows never stored)
  else if (i == 0 || j == 0) val = 1.f;  // cls row/col of ones
  else {
    float acc = 0.f;
#pragma unroll
    for (int c = 0; c < 6; ++c) {
      float a  = ai[c * 12 + h];
      float p  = 1.f / (1.f + expf(-a));
      float l2 = log2f(p);
      int   e  = ci[c * 196 + i - 1] - ci[c * 196 + j - 1];
      if (e < 0) e = -e;
      acc += exp2f(l2 * (float)e);
    }
    val = acc * (1.f / 6.f);
  }
  Mb[((size_t)h * NKV + i) * NKV + j] = f2bf(val);
}

// ---------------- 128x128 tile bf16 GEMM (m97 structure, BK=64, XOR-swizzled LDS) ----
// EPI=0: qkv -> scatter into Q/K/V [bh][224][64] (bf16, all natural layout)
// EPI=1: proj -> f32 out + bias
// XCD-aware bijective block swizzle (T1, m204 formula).
template <int EPI, int NT>
__global__ __launch_bounds__(256) void gemm128(
    const ushort* __restrict__ A, const ushort* __restrict__ Bw,
    ushort* __restrict__ Qb, ushort* __restrict__ Kb, ushort* __restrict__ Vb,
    const float* __restrict__ bias, float* __restrict__ outp, int nwg) {
  __shared__ alignas(16) char As[128 * 128];
  __shared__ alignas(16) char Bs[128 * 128];
  const int tid = threadIdx.x;
  const int lane = tid & 63, wid = tid >> 6;
  const int g = lane >> 4, li = lane & 15;
  // bijective XCD swizzle: consecutive wgid on one XCD -> shared A-panel in its L2
  const int q8 = nwg >> 3, r8 = nwg & 7;
  const int xcd = blockIdx.x & 7, sidx = blockIdx.x >> 3;
  const int wgid = (xcd < r8 ? xcd * (q8 + 1) : r8 * (q8 + 1) + (xcd - r8) * q8) + sidx;
  const int m0 = (wgid / NT) * 128;
  const int n0 = (wgid % NT) * 128;
  const int wr = wid >> 1, wc = wid & 1;

  f32x4 acc[4][4];
  f32x4 zero = {0.f, 0.f, 0.f, 0.f};
#pragma unroll
  for (int i = 0; i < 4; ++i)
#pragma unroll
    for (int j = 0; j < 4; ++j) acc[i][j] = zero;

  for (int kk = 0; kk < 768; kk += 64) {
    // stage A,B tiles: linear LDS dest, inverse-XOR-swizzled global source (m173)
#pragma unroll
    for (int p = 0; p < 4; ++p) {
      int o = tid * 16 + p * 4096;           // byte offset in 16KB tile
      int row = o >> 7;
      int cs = (o & 127) ^ ((row & 7) << 4);
      gload_lds16(A + (size_t)(m0 + row) * 768 + kk + (cs >> 1), As + o);
      gload_lds16(Bw + (size_t)(n0 + row) * 768 + kk + (cs >> 1), Bs + o);
    }
    __syncthreads();
#pragma unroll
    for (int ks = 0; ks < 2; ++ks) {
      bf16x8 af[4], bfr[4];
#pragma unroll
      for (int mt = 0; mt < 4; ++mt) {
        int row = wr * 64 + mt * 16 + li;
        int c = (ks * 64 + g * 16) ^ ((row & 7) << 4);
        af[mt] = *(const bf16x8*)(As + row * 128 + c);
      }
#pragma unroll
      for (int nt = 0; nt < 4; ++nt) {
        int row = wc * 64 + nt * 16 + li;
        int c = (ks * 64 + g * 16) ^ ((row & 7) << 4);
        bfr[nt] = *(const bf16x8*)(Bs + row * 128 + c);
      }
#pragma unroll
      for (int mt = 0; mt < 4; ++mt)
#pragma unroll
        for (int nt = 0; nt < 4; ++nt)
          acc[mt][nt] = __builtin_amdgcn_mfma_f32_16x16x32_bf16(
              af[mt], bfr[nt], acc[mt][nt], 0, 0, 0);
    }
    __syncthreads();
  }

  if (EPI == 0) {
    const int s3 = n0 / 768;   // 0=q, 1=k, 2=v (block-uniform: 128 | 768)
    ushort* dst = (s3 == 0) ? Qb : (s3 == 1) ? Kb : Vb;
#pragma unroll
    for (int nt = 0; nt < 4; ++nt) {
      int n = n0 + wc * 64 + nt * 16 + li;
      int rem = n - s3 * 768;
      int hh = rem >> 6, d = rem & 63;
#pragma unroll
      for (int mt = 0; mt < 4; ++mt) {
#pragma unroll
        for (int r = 0; r < 4; ++r) {
          int m = m0 + wr * 64 + mt * 16 + 4 * g + r;
          uint32_t bI = ((uint32_t)m * 85164u) >> 24;  // m/197 (exact for m<25216)
          int tok = m - (int)bI * 197;
          size_t bh = (size_t)bI * 12 + hh;
          dst[(bh * NKV + tok) * 64 + d] = f2bf(acc[mt][nt][r]);
        }
      }
    }
  } else {
#pragma unroll
    for (int nt = 0; nt < 4; ++nt) {
      int n = n0 + wc * 64 + nt * 16 + li;
      float bv = bias[n];
#pragma unroll
      for (int mt = 0; mt < 4; ++mt) {
#pragma unroll
        for (int r = 0; r < 4; ++r) {
          int m = m0 + wr * 64 + mt * 16 + 4 * g + r;
          outp[(size_t)m * 768 + n] = acc[mt][nt][r] + bv;
        }
      }
    }
  }
}

// ---------------- fused masked attention, one block per (b,h) --------------------
// Swapped QK^T: S^T = mfma(K, Q^T) so each lane owns one q-row (i = lane&15);
// softmax reduce = 2x shfl_xor. K and Q read straight from global (L1/L2-resident,
// 28KB per bh -- Common-mistake #7: don't stage cache-fit data). V transposed into
// LDS at stage time. P staged per-wave in LDS for the PV A-fragment.
// LDS = Vl 29696B + Pl 51968B = 81664B <= 81920 -> 2 blocks/CU.
#define VL_S 232   // Vl row stride (ushorts): 464B -> reads 2-way banks max
__global__ __launch_bounds__(448, 4) void attn_kernel(
    const ushort* __restrict__ Qb, const ushort* __restrict__ Kb,
    const ushort* __restrict__ Vb, const ushort* __restrict__ Mb,
    ushort* __restrict__ Ob) {
  __shared__ alignas(16) ushort Vl[64 * VL_S];      // 29696 B (V^T: [d][tok])
  __shared__ alignas(16) ushort Pl[7 * 16 * VL_S];  // 51968 B
  const int tid = threadIdx.x, lane = tid & 63, wid = tid >> 6;
  const int g = lane >> 4, li = lane & 15;
  const int bh = blockIdx.x;
  const int b = bh / 12, h = bh % 12;

  const ushort* Kg = Kb + (size_t)bh * (NKV * 64);
  const ushort* Vg = Vb + (size_t)bh * (NKV * 64);
  const ushort* Qg = Qb + (size_t)bh * (NKV * 64);

  // stage V [224][64] -> transposed Vl [64][VL_S]
#pragma unroll
  for (int p = 0; p < 4; ++p) {
    int o = (tid + p * 448) * 16;               // byte offset, 28672 total
    int tok = o >> 7;
    int d0 = (o >> 1) & 63;                     // 8*sub
    u16x8 v = *(const u16x8*)((const char*)Vg + o);
#pragma unroll
    for (int j = 0; j < 8; ++j)
      Vl[(d0 + j) * VL_S + tok] = v[j];
  }
  __syncthreads();

  for (int t = 0; t < 2; ++t) {
    int rt = wid * 2 + t;                       // 14 row-tiles over 7 waves
    int r0 = rt * 16;
    if (r0 >= 197) continue;                    // tile 13 fully padded
    // Q fragments straight from global (read once, reused 14x)
    bf16x8 qf[2];
#pragma unroll
    for (int ks = 0; ks < 2; ++ks)
      qf[ks] = *(const bf16x8*)(Qg + (size_t)(r0 + li) * 64 + ks * 32 + g * 8);

    // S^T: acc[ct] holds (j = ct*16+4g+r, i = r0+li); K fragments from global
    f32x4 acc[14];
#pragma unroll
    for (int ct = 0; ct < 14; ++ct) {
      bf16x8 kf0 = *(const bf16x8*)(Kg + (size_t)(ct * 16 + li) * 64 + g * 8);
      bf16x8 kf1 = *(const bf16x8*)(Kg + (size_t)(ct * 16 + li) * 64 + 32 + g * 8);
      f32x4 z = {0.f, 0.f, 0.f, 0.f};
      z = __builtin_amdgcn_mfma_f32_16x16x32_bf16(kf0, qf[0], z, 0, 0, 0);
      acc[ct] = __builtin_amdgcn_mfma_f32_16x16x32_bf16(kf1, qf[1], z, 0, 0, 0);
    }

    // logits in place: L = (S * 1/8) * M[h][i][j]; -1e30 for j>=197
    int ig = r0 + li;
    const ushort* Mrow = Mb + ((size_t)h * NKV + ig) * NKV;
    float mx = -3e38f;
#pragma unroll
    for (int ct = 0; ct < 14; ++ct) {
      int j0 = ct * 16 + 4 * g;
      ushort4 mv = *(const ushort4*)(Mrow + j0);
#pragma unroll
      for (int r = 0; r < 4; ++r) {
        float Lv = (j0 + r < 197)
                     ? acc[ct][r] * 0.125f * bf2f(((const ushort*)&mv)[r])
                     : -1e30f;
        acc[ct][r] = Lv;
        mx = fmaxf(mx, Lv);
      }
    }
    mx = fmaxf(mx, __shfl_xor(mx, 16));
    mx = fmaxf(mx, __shfl_xor(mx, 32));

    float sum = 0.f;
    ushort* Prow = Pl + ((size_t)wid * 16 + li) * VL_S;
#pragma unroll
    for (int ct = 0; ct < 14; ++ct) {
      ushort4 pv;
#pragma unroll
      for (int r = 0; r < 4; ++r) {
        float p = exp2f((acc[ct][r] - mx) * 1.44269504f);  // 0 for masked j
        sum += p;
        ((ushort*)&pv)[r] = f2bf(p);
      }
      *(ushort4*)(Prow + ct * 16 + 4 * g) = pv;            // 8B store
    }
    sum += __shfl_xor(sum, 16);
    sum += __shfl_xor(sum, 32);

    asm volatile("s_waitcnt lgkmcnt(0)" ::: "memory");     // P visible to own wave
    __builtin_amdgcn_sched_barrier(0);

    // PV: O[i][d] = P @ V, A=P (row=i=li), B=V^T (col=d=li)
    f32x4 oacc[4];
#pragma unroll
    for (int dt = 0; dt < 4; ++dt) oacc[dt] = (f32x4){0.f, 0.f, 0.f, 0.f};
    const ushort* Pbase = Pl + (size_t)wid * 16 * VL_S;
#pragma unroll
    for (int ks = 0; ks < 7; ++ks) {
      bf16x8 pf = *(const bf16x8*)(Pbase + (size_t)li * VL_S + ks * 32 + g * 8);
#pragma unroll
      for (int dt = 0; dt < 4; ++dt) {
        bf16x8 vf = *(const bf16x8*)(Vl + (size_t)(dt * 16 + li) * VL_S + ks * 32 + g * 8);
        oacc[dt] = __builtin_amdgcn_mfma_f32_16x16x32_bf16(pf, vf, oacc[dt], 0, 0, 0);
      }
    }
    // normalize + store (D rows i_local = 4g+r; rowsum lives in lane (4g+r))
    float inv[4];
#pragma unroll
    for (int r = 0; r < 4; ++r) {
      float sr = __shfl(sum, 4 * g + r);
      inv[r] = 1.f / sr;
    }
#pragma unroll
    for (int dt = 0; dt < 4; ++dt) {
      int d = dt * 16 + li;
#pragma unroll
      for (int r = 0; r < 4; ++r) {
        int tokn = r0 + 4 * g + r;
        if (tokn < 197) {
          size_t rowi = (size_t)b * 197 + tokn;
          Ob[rowi * 768 + h * 64 + d] = f2bf(oacc[dt][r] * inv[r]);
        }
      }
    }
  }
}

// ---------------- host ----------------
extern "C" void kernel_launch(void* const* d_in, const int* in_sizes, int n_in,
                              void* d_out, int out_size, void* d_ws, size_t ws_size,
                              hipStream_t stream) {
  const float* x      = (const float*)d_in[0];
  const float* w_qkv  = (const float*)d_in[1];
  const float* w_proj = (const float*)d_in[2];
  const float* b_proj = (const float*)d_in[3];
  const float* ai     = (const float*)d_in[4];
  const int*   ci     = (const int*)d_in[5];
  float* out = (float*)d_out;

  // ws layout (ushort elements)
  ushort* x_bf    = (ushort*)d_ws;                          // 25216*768
  ushort* wqkv_bf = x_bf + (size_t)TOK * CC;                // 2304*768
  ushort* wproj_bf= wqkv_bf + (size_t)2304 * CC;            // 768*768
  ushort* Qb      = wproj_bf + (size_t)CC * CC;             // 1536*224*64
  ushort* Kb      = Qb + (size_t)BHN * NKV * 64;
  ushort* Vb      = Kb + (size_t)BHN * NKV * 64;
  ushort* Mb      = Vb + (size_t)BHN * NKV * 64;            // 12*224*224
  ushort* Ob      = x_bf;  // reuse: x_bf dead after qkv GEMM

  conv_bf16<<<(TOK * CC / 4 + 255) / 256, 256, 0, stream>>>(x, x_bf, TOK * CC);
  conv_bf16<<<(2304 * CC / 4 + 255) / 256, 256, 0, stream>>>(w_qkv, wqkv_bf, 2304 * CC);
  conv_bf16<<<(CC * CC / 4 + 255) / 256, 256, 0, stream>>>(w_proj, wproj_bf, CC * CC);
  mask_kernel<<<12 * NKV, 256, 0, stream>>>(ai, ci, Mb);
  gemm128<0, 18><<<197 * 18, 256, 0, stream>>>(x_bf, wqkv_bf, Qb, Kb, Vb, nullptr, nullptr, 197 * 18);
  attn_kernel<<<BHN, 448, 0, stream>>>(Qb, Kb, Vb, Mb, Ob);
  gemm128<1, 6><<<197 * 6, 256, 0, stream>>>(Ob, wproj_bf, nullptr, nullptr, nullptr, b_proj, out, 197 * 6);
}

// Round 7
// 395.530 us; speedup vs baseline: 1.2058x; 1.2058x over previous
//
#include <hip/hip_runtime.h>
#include <hip/hip_bf16.h>
#include <stdint.h>

// Problem constants
#define TOK   25216          // B*N = 128*197
#define CC    768
#define HH    12
#define NKV   224            // 197 padded to 14*16 (and 7*32 for PV k-steps)
#define BHN   1536           // B*H

typedef __attribute__((ext_vector_type(8))) __bf16 bf16x8;   // MFMA A/B frag (4 VGPR)
typedef __attribute__((ext_vector_type(8))) ushort u16x8;
typedef __attribute__((ext_vector_type(4))) float  f32x4;    // MFMA C/D frag
typedef __attribute__((ext_vector_type(4))) uint32_t u32x4;

__device__ __forceinline__ ushort f2bf(float f) {
  union { float f; uint32_t u; } v; v.f = f;
  uint32_t u = v.u;
  u += 0x7FFFu + ((u >> 16) & 1u);          // RTNE
  return (ushort)(u >> 16);
}
__device__ __forceinline__ float bf2f(ushort s) {
  union { uint32_t u; float f; } v; v.u = ((uint32_t)s) << 16; return v.f;
}

__device__ __forceinline__ void gload_lds16(const void* g, void* l) {
  __builtin_amdgcn_global_load_lds(
      (const __attribute__((address_space(1))) unsigned int*)g,
      (__attribute__((address_space(3))) unsigned int*)l, 16, 0, 0);
}

// ---------------- f32 -> bf16 convert (vectorized) ----------------
__global__ __launch_bounds__(256) void conv_bf16(const float* __restrict__ in,
                                                 ushort* __restrict__ out, int n) {
  int idx = (blockIdx.x * 256 + threadIdx.x) * 4;
  if (idx < n) {
    float4 v = *(const float4*)(in + idx);
    ushort4 o;
    o.x = f2bf(v.x); o.y = f2bf(v.y); o.z = f2bf(v.z); o.w = f2bf(v.w);
    *(ushort4*)(out + idx) = o;
  }
}

// ---------------- decay mask: M[h][i][j], padded [12][224][224] bf16 ----------------
__global__ __launch_bounds__(256) void mask_kernel(const float* __restrict__ ai,
                                                   const int* __restrict__ ci,
                                                   ushort* __restrict__ Mb) {
  int h = blockIdx.x / NKV;
  int i = blockIdx.x % NKV;
  int j = threadIdx.x;
  if (j >= NKV) return;
  float val;
  if (j >= 197)      val = 0.f;   // unused (forced -inf logit)
  else if (i >= 197) val = 1.f;   // unused (rows never stored)
  else if (i == 0 || j == 0) val = 1.f;  // cls row/col of ones
  else {
    float acc = 0.f;
#pragma unroll
    for (int c = 0; c < 6; ++c) {
      float a  = ai[c * 12 + h];
      float p  = 1.f / (1.f + expf(-a));
      float l2 = log2f(p);
      int   e  = ci[c * 196 + i - 1] - ci[c * 196 + j - 1];
      if (e < 0) e = -e;
      acc += exp2f(l2 * (float)e);
    }
    val = acc * (1.f / 6.f);
  }
  Mb[((size_t)h * NKV + i) * NKV + j] = f2bf(val);
}

// ---------------- 128x128 tile bf16 GEMM (m97 structure, BK=64, XOR-swizzled LDS) ----
// EPI=0: qkv -> scatter into Q/K/V [bh][224][64] (bf16, all natural layout)
// EPI=1: proj -> f32 out + bias
// XCD-aware bijective block swizzle (T1, m204 formula).
template <int EPI, int NT>
__global__ __launch_bounds__(256) void gemm128(
    const ushort* __restrict__ A, const ushort* __restrict__ Bw,
    ushort* __restrict__ Qb, ushort* __restrict__ Kb, ushort* __restrict__ Vb,
    const float* __restrict__ bias, float* __restrict__ outp, int nwg) {
  __shared__ alignas(16) char As[128 * 128];
  __shared__ alignas(16) char Bs[128 * 128];
  const int tid = threadIdx.x;
  const int lane = tid & 63, wid = tid >> 6;
  const int g = lane >> 4, li = lane & 15;
  // bijective XCD swizzle: consecutive wgid on one XCD -> shared A-panel in its L2
  const int q8 = nwg >> 3, r8 = nwg & 7;
  const int xcd = blockIdx.x & 7, sidx = blockIdx.x >> 3;
  const int wgid = (xcd < r8 ? xcd * (q8 + 1) : r8 * (q8 + 1) + (xcd - r8) * q8) + sidx;
  const int m0 = (wgid / NT) * 128;
  const int n0 = (wgid % NT) * 128;
  const int wr = wid >> 1, wc = wid & 1;

  f32x4 acc[4][4];
  f32x4 zero = {0.f, 0.f, 0.f, 0.f};
#pragma unroll
  for (int i = 0; i < 4; ++i)
#pragma unroll
    for (int j = 0; j < 4; ++j) acc[i][j] = zero;

  for (int kk = 0; kk < 768; kk += 64) {
    // stage A,B tiles: linear LDS dest, inverse-XOR-swizzled global source (m173)
#pragma unroll
    for (int p = 0; p < 4; ++p) {
      int o = tid * 16 + p * 4096;           // byte offset in 16KB tile
      int row = o >> 7;
      int cs = (o & 127) ^ ((row & 7) << 4);
      gload_lds16(A + (size_t)(m0 + row) * 768 + kk + (cs >> 1), As + o);
      gload_lds16(Bw + (size_t)(n0 + row) * 768 + kk + (cs >> 1), Bs + o);
    }
    __syncthreads();
#pragma unroll
    for (int ks = 0; ks < 2; ++ks) {
      bf16x8 af[4], bfr[4];
#pragma unroll
      for (int mt = 0; mt < 4; ++mt) {
        int row = wr * 64 + mt * 16 + li;
        int c = (ks * 64 + g * 16) ^ ((row & 7) << 4);
        af[mt] = *(const bf16x8*)(As + row * 128 + c);
      }
#pragma unroll
      for (int nt = 0; nt < 4; ++nt) {
        int row = wc * 64 + nt * 16 + li;
        int c = (ks * 64 + g * 16) ^ ((row & 7) << 4);
        bfr[nt] = *(const bf16x8*)(Bs + row * 128 + c);
      }
#pragma unroll
      for (int mt = 0; mt < 4; ++mt)
#pragma unroll
        for (int nt = 0; nt < 4; ++nt)
          acc[mt][nt] = __builtin_amdgcn_mfma_f32_16x16x32_bf16(
              af[mt], bfr[nt], acc[mt][nt], 0, 0, 0);
    }
    __syncthreads();
  }

  if (EPI == 0) {
    const int s3 = n0 / 768;   // 0=q, 1=k, 2=v (block-uniform: 128 | 768)
    ushort* dst = (s3 == 0) ? Qb : (s3 == 1) ? Kb : Vb;
#pragma unroll
    for (int nt = 0; nt < 4; ++nt) {
      int n = n0 + wc * 64 + nt * 16 + li;
      int rem = n - s3 * 768;
      int hh = rem >> 6, d = rem & 63;
#pragma unroll
      for (int mt = 0; mt < 4; ++mt) {
#pragma unroll
        for (int r = 0; r < 4; ++r) {
          int m = m0 + wr * 64 + mt * 16 + 4 * g + r;
          uint32_t bI = ((uint32_t)m * 85164u) >> 24;  // m/197 (exact for m<25216)
          int tok = m - (int)bI * 197;
          size_t bh = (size_t)bI * 12 + hh;
          dst[(bh * NKV + tok) * 64 + d] = f2bf(acc[mt][nt][r]);
        }
      }
    }
  } else {
#pragma unroll
    for (int nt = 0; nt < 4; ++nt) {
      int n = n0 + wc * 64 + nt * 16 + li;
      float bv = bias[n];
#pragma unroll
      for (int mt = 0; mt < 4; ++mt) {
#pragma unroll
        for (int r = 0; r < 4; ++r) {
          int m = m0 + wr * 64 + mt * 16 + 4 * g + r;
          outp[(size_t)m * 768 + n] = acc[mt][nt][r] + bv;
        }
      }
    }
  }
}

// ---------------- fused masked attention, one block per (b,h) --------------------
// Swapped QK^T: S^T = mfma(K, Q^T) so each lane owns one q-row (i = lane&15);
// softmax reduce = 2x shfl_xor. K staged in LDS (stride 72 = conflict-free).
// P stays IN REGISTER: cvt_pk_bf16 pack + 2-stage shfl butterfly rearranges
// P[i=li][j=ct*16+4g+r] into the PV A-fragment (lane g,li needs j=ks*32+g*8+u,
// i.e. words from lanes gs={2(g&1),2(g&1)+1} at ct=2ks+(g>>1)).
// O staged through per-wave LDS so global stores are full 128-B lines.
// LDS = Kl 32256 + Vl 29696 + Ol 14784 = 76736 B -> 2 blocks/CU.
#define KL_S 72    // Kl row stride (ushorts): 144B -> 2-way banks max
#define VL_S 232   // Vl row stride (ushorts): 464B -> 2-way banks max
#define OL_S 66    // Ol row stride (ushorts)
__global__ __launch_bounds__(448, 4) void attn_kernel(
    const ushort* __restrict__ Qb, const ushort* __restrict__ Kb,
    const ushort* __restrict__ Vb, const ushort* __restrict__ Mb,
    ushort* __restrict__ Ob) {
  __shared__ alignas(16) ushort Kl[NKV * KL_S];      // 32256 B
  __shared__ alignas(16) ushort Vl[64 * VL_S];       // 29696 B (V^T: [d][tok])
  __shared__ alignas(16) ushort Olds[7 * 16 * OL_S]; // 14784 B
  const int tid = threadIdx.x, lane = tid & 63, wid = tid >> 6;
  const int g = lane >> 4, li = lane & 15;
  const int bh = blockIdx.x;
  const int b = bh / 12, h = bh % 12;

  const ushort* Kg = Kb + (size_t)bh * (NKV * 64);
  const ushort* Vg = Vb + (size_t)bh * (NKV * 64);
  const ushort* Qg = Qb + (size_t)bh * (NKV * 64);

  // Q issue-early: both row-tiles' fragments (latency hides under staging)
  bf16x8 qfa[2][2];
#pragma unroll
  for (int t = 0; t < 2; ++t) {
    int r0 = (wid * 2 + t) * 16;
    qfa[t][0] = *(const bf16x8*)(Qg + (size_t)(r0 + li) * 64 + g * 8);
    qfa[t][1] = *(const bf16x8*)(Qg + (size_t)(r0 + li) * 64 + 32 + g * 8);
  }

  // stage K [224][64] -> Kl rows (stride 72), 16B chunks
#pragma unroll
  for (int p = 0; p < 4; ++p) {
    int o = (tid + p * 448) * 16;               // byte offset, 28672 total
    int row = o >> 7, c = o & 127;
    *(bf16x8*)((char*)Kl + row * 144 + c) = *(const bf16x8*)((const char*)Kg + o);
  }
  // stage V [224][64] -> transposed Vl [64][VL_S]
#pragma unroll
  for (int p = 0; p < 4; ++p) {
    int o = (tid + p * 448) * 16;
    int tok = o >> 7;
    int d0 = (o >> 1) & 63;
    u16x8 v = *(const u16x8*)((const char*)Vg + o);
#pragma unroll
    for (int j = 0; j < 8; ++j)
      Vl[(d0 + j) * VL_S + tok] = v[j];
  }
  __syncthreads();

  for (int t = 0; t < 2; ++t) {
    int rt = wid * 2 + t;                       // 14 row-tiles over 7 waves
    int r0 = rt * 16;
    if (r0 >= 197) continue;                    // tile 13 fully padded

    // S^T: acc[ct] holds (j = ct*16+4g+r, i = r0+li)
    f32x4 acc[14];
#pragma unroll
    for (int ct = 0; ct < 14; ++ct) {
      bf16x8 kf0 = *(const bf16x8*)((const char*)Kl + (ct * 16 + li) * 144 + g * 16);
      bf16x8 kf1 = *(const bf16x8*)((const char*)Kl + (ct * 16 + li) * 144 + 64 + g * 16);
      f32x4 z = {0.f, 0.f, 0.f, 0.f};
      z = __builtin_amdgcn_mfma_f32_16x16x32_bf16(kf0, qfa[t][0], z, 0, 0, 0);
      acc[ct] = __builtin_amdgcn_mfma_f32_16x16x32_bf16(kf1, qfa[t][1], z, 0, 0, 0);
    }

    // logits in place: L = (S * 1/8) * M[h][i][j]; -1e30 for j>=197
    int ig = r0 + li;
    const ushort* Mrow = Mb + ((size_t)h * NKV + ig) * NKV;
    float mx = -3e38f;
#pragma unroll
    for (int ct = 0; ct < 14; ++ct) {
      int j0 = ct * 16 + 4 * g;
      ushort4 mv = *(const ushort4*)(Mrow + j0);
#pragma unroll
      for (int r = 0; r < 4; ++r) {
        float Lv = (j0 + r < 197)
                     ? acc[ct][r] * 0.125f * bf2f(((const ushort*)&mv)[r])
                     : -1e30f;
        acc[ct][r] = Lv;
        mx = fmaxf(mx, Lv);
      }
    }
    mx = fmaxf(mx, __shfl_xor(mx, 16));
    mx = fmaxf(mx, __shfl_xor(mx, 32));

    // exp + pack P to bf16 pairs entirely in register
    float sum = 0.f;
    uint32_t q0w[14], q1w[14];   // q0w: (r0,r1) packed; q1w: (r2,r3)
#pragma unroll
    for (int ct = 0; ct < 14; ++ct) {
      float p0 = exp2f((acc[ct][0] - mx) * 1.44269504f);
      float p1 = exp2f((acc[ct][1] - mx) * 1.44269504f);
      float p2 = exp2f((acc[ct][2] - mx) * 1.44269504f);
      float p3 = exp2f((acc[ct][3] - mx) * 1.44269504f);
      sum += (p0 + p1) + (p2 + p3);
      asm("v_cvt_pk_bf16_f32 %0, %1, %2" : "=v"(q0w[ct]) : "v"(p0), "v"(p1));
      asm("v_cvt_pk_bf16_f32 %0, %1, %2" : "=v"(q1w[ct]) : "v"(p2), "v"(p3));
    }
    sum += __shfl_xor(sum, 16);
    sum += __shfl_xor(sum, 32);

    // PV: O[i][d] = P @ V. A-frag assembled via 2-stage shfl butterfly.
    f32x4 oacc[4];
#pragma unroll
    for (int dt = 0; dt < 4; ++dt) oacc[dt] = (f32x4){0.f, 0.f, 0.f, 0.f};
#pragma unroll
    for (int ks = 0; ks < 7; ++ks) {
      uint32_t E0 = q0w[2 * ks], Ov0 = q0w[2 * ks + 1];
      uint32_t E1 = q1w[2 * ks], Ov1 = q1w[2 * ks + 1];
      // stage 1 (xor 32): Ea = [e@0,e@1,o@0,o@1], Oa = [e@2,e@3,o@2,o@3] per g
      uint32_t sO0 = __shfl_xor(Ov0, 32), sE0 = __shfl_xor(E0, 32);
      uint32_t sO1 = __shfl_xor(Ov1, 32), sE1 = __shfl_xor(E1, 32);
      uint32_t Ea0 = (lane < 32) ? E0 : sO0;
      uint32_t Oa0 = (lane < 32) ? sE0 : Ov0;
      uint32_t Ea1 = (lane < 32) ? E1 : sO1;
      uint32_t Oa1 = (lane < 32) ? sE1 : Ov1;
      // stage 2 (xor 16) + parity select
      uint32_t tOa0 = __shfl_xor(Oa0, 16), tEa0 = __shfl_xor(Ea0, 16);
      uint32_t tOa1 = __shfl_xor(Oa1, 16), tEa1 = __shfl_xor(Ea1, 16);
      uint32_t w0 = (g & 1) ? tOa0 : Ea0;   // gs0 pk(r0,r1)
      uint32_t w1 = (g & 1) ? tOa1 : Ea1;   // gs0 pk(r2,r3)
      uint32_t w2 = (g & 1) ? Oa0 : tEa0;   // gs1 pk(r0,r1)
      uint32_t w3 = (g & 1) ? Oa1 : tEa1;   // gs1 pk(r2,r3)
      u32x4 aw = {w0, w1, w2, w3};
      bf16x8 af = __builtin_bit_cast(bf16x8, aw);
#pragma unroll
      for (int dt = 0; dt < 4; ++dt) {
        bf16x8 vf = *(const bf16x8*)(Vl + (size_t)(dt * 16 + li) * VL_S + ks * 32 + g * 8);
        oacc[dt] = __builtin_amdgcn_mfma_f32_16x16x32_bf16(af, vf, oacc[dt], 0, 0, 0);
      }
    }

    // normalize, stage in per-wave LDS, store coalesced (full 128B rows)
    float inv4[4];
#pragma unroll
    for (int r = 0; r < 4; ++r) inv4[r] = 1.f / __shfl(sum, 4 * g + r);
    ushort* Ow = Olds + wid * 16 * OL_S;
#pragma unroll
    for (int dt = 0; dt < 4; ++dt)
#pragma unroll
      for (int r = 0; r < 4; ++r)
        Ow[(4 * g + r) * OL_S + dt * 16 + li] = f2bf(oacc[dt][r] * inv4[r]);
    asm volatile("s_waitcnt lgkmcnt(0)" ::: "memory");   // wave-private region
    __builtin_amdgcn_sched_barrier(0);
#pragma unroll
    for (int it = 0; it < 2; ++it) {
      int row = it * 8 + (lane >> 3);
      int ch = lane & 7;
      u16x8 ov = *(const u16x8*)(Ow + row * OL_S + ch * 8);
      int tokn = r0 + row;
      if (tokn < 197)
        *(u16x8*)(Ob + ((size_t)b * 197 + tokn) * 768 + h * 64 + ch * 8) = ov;
    }
  }
}

// ---------------- host ----------------
extern "C" void kernel_launch(void* const* d_in, const int* in_sizes, int n_in,
                              void* d_out, int out_size, void* d_ws, size_t ws_size,
                              hipStream_t stream) {
  const float* x      = (const float*)d_in[0];
  const float* w_qkv  = (const float*)d_in[1];
  const float* w_proj = (const float*)d_in[2];
  const float* b_proj = (const float*)d_in[3];
  const float* ai     = (const float*)d_in[4];
  const int*   ci     = (const int*)d_in[5];
  float* out = (float*)d_out;

  // ws layout (ushort elements)
  ushort* x_bf    = (ushort*)d_ws;                          // 25216*768
  ushort* wqkv_bf = x_bf + (size_t)TOK * CC;                // 2304*768
  ushort* wproj_bf= wqkv_bf + (size_t)2304 * CC;            // 768*768
  ushort* Qb      = wproj_bf + (size_t)CC * CC;             // 1536*224*64
  ushort* Kb      = Qb + (size_t)BHN * NKV * 64;
  ushort* Vb      = Kb + (size_t)BHN * NKV * 64;
  ushort* Mb      = Vb + (size_t)BHN * NKV * 64;            // 12*224*224
  ushort* Ob      = x_bf;  // reuse: x_bf dead after qkv GEMM

  conv_bf16<<<(TOK * CC / 4 + 255) / 256, 256, 0, stream>>>(x, x_bf, TOK * CC);
  conv_bf16<<<(2304 * CC / 4 + 255) / 256, 256, 0, stream>>>(w_qkv, wqkv_bf, 2304 * CC);
  conv_bf16<<<(CC * CC / 4 + 255) / 256, 256, 0, stream>>>(w_proj, wproj_bf, CC * CC);
  mask_kernel<<<12 * NKV, 256, 0, stream>>>(ai, ci, Mb);
  gemm128<0, 18><<<197 * 18, 256, 0, stream>>>(x_bf, wqkv_bf, Qb, Kb, Vb, nullptr, nullptr, 197 * 18);
  attn_kernel<<<BHN, 448, 0, stream>>>(Qb, Kb, Vb, Mb, Ob);
  gemm128<1, 6><<<197 * 6, 256, 0, stream>>>(Ob, wproj_bf, nullptr, nullptr, nullptr, b_proj, out, 197 * 6);
}